// Round 8
// baseline (279.243 us; speedup 1.0000x reference)
//
#include <hip/hip_runtime.h>

// SNN forward scan: B=64, N=1024, T=512. Row = (b*N+n), x[row*512 + t].
//
// R15: FULL-ROW SEQUENTIAL READS. R8-R14 falsified barriers, write
// pattern, queue depth, channel skew, staging mechanism — every variant
// serves the read stream at 2.0-2.3 TB/s. Last un-isolated variable: the
// 256-B granule @ 2-KiB stride (1/4 of each ~1-KiB HBM page per
// activation -> ~25-35% DRAM efficiency ~= measured). This kernel reads
// FULL rows: block = 1 wave, 16 consecutive rows, one 32-KiB perfectly
// contiguous span per block (DMA global_load_lds, 1-KiB-linear per
// instr). LDS = 32 KiB exactly -> 5 blocks/CU; 4096 blocks desynchronize
// naturally (no barriers anywhere: 1-wave lockstep) -> continuous
// sequential burst traffic, no phase convoy.
//   - compute: lanes 0-15, one row per lane, full 512-step scan from LDS;
//     wave time is chain-bound so 48 masked lanes cost nothing.
//   - per-row XOR quad-swizzle q^(L&7), source-pre-swizzled (G21
//     both-sides): compute's stride-2KiB reads -> 2-way banks (free).
//   - 2-quad software prefetch (~190 cyc) covers LDS latency.
//   - spikes overwrite consumed x in LDS (b128 write per 4 steps);
//     writeout = 32-KiB contiguous NT burst (lane-permuted LDS reads).
// Predicted: FETCH ~65MB WRITE ~131MB unchanged; VGPR 56-72; conflicts
// <0.3M; VALUBusy 25-35%; dur 88 -> 45-60us if page-efficiency theory
// right; 80-95 kills the last pattern suspect -> declare ~2.2-2.4 TB/s
// the empirical service rate (roofline).
//
// Numerics: BIT-EXACT vs float32 reference (identical per-row op order;
// spikes stored as exact 0.0f/1.0f). contract(off).
#pragma clang fp contract(off)

#define ROWSB   16                    // rows per block (1 wave; lanes 0-15 compute)
#define T_LEN   512
#define QPR     128                   // float4 quads per row
#define NPARAM  1024

typedef float f4_nt __attribute__((ext_vector_type(4)));

// async global->LDS DMA, 16 B per lane: LDS dest = uniform base + lane*16
#define GLOAD16(gp, lp)                                                \
    __builtin_amdgcn_global_load_lds(                                  \
        (const __attribute__((address_space(1))) void*)(gp),           \
        (__attribute__((address_space(3))) void*)(lp), 16, 0, 0)

__global__ __launch_bounds__(64) void snn_fwd(
    const float* __restrict__ x,
    const float* __restrict__ beta,
    const float* __restrict__ p,
    const float* __restrict__ bparam,
    float* __restrict__ out)
{
    __shared__ __align__(16) float4 xbuf[ROWSB * QPR];   // 32768 B exactly

    const int lane    = threadIdx.x;            // 0..63
    const int rowBase = blockIdx.x * ROWSB;

    const float4* __restrict__ xq = (const float4*)x + (size_t)rowBase * QPR;
    float4* __restrict__ oq       = (float4*)out + (size_t)rowBase * QPR;

    // ---- stage: one 32-KiB contiguous span, 32 DMA instrs of 1 KiB ----
    // instr j: LDS quads [j*64, j*64+63] (lane-linear) = row L=j>>1,
    // half h=j&1. Want LDS slot q to hold global quad q^(L&7) of row L:
    // per-lane global quad = ((h<<6)|lane) ^ (L&7)  (permutes within 128 B
    // -> the instr still covers one aligned contiguous 1-KiB chunk).
    #pragma unroll
    for (int j = 0; j < 2 * ROWSB; ++j) {
        const int L  = j >> 1;
        const int qg = (((j & 1) << 6) | lane) ^ (L & 7);
        GLOAD16(xq + L * QPR + qg, (float*)xbuf + j * 256);
    }

    // clamped params (while DMA flies); lanes 16-63 compute unused copies
    float beta_c, p_c, b_c;
    {
        const int n = (rowBase + (lane & (ROWSB - 1))) & (NPARAM - 1);
        beta_c = fminf(fmaxf(beta[n], 0.001f), 0.999f);
        p_c    = fminf(fabsf(p[n]), 0.999f);
        b_c    = fminf(fmaxf(fabsf(bparam[n]), 0.001f), 1.0f);
    }

    float mem = 0.0f, refac = 2.0f, a = 0.0f, vth = 1.0f, ps = 0.0f;

    auto step = [&](float xt) -> float {
        refac = (ps > 0.0f) ? 0.0f : refac;           // spike-triggered reset
        const float ic = (refac < 2.0f) ? 0.0f : xt;  // refractory input mask
        refac += 1.0f;
        const float nm   = __fadd_rn(__fmul_rn(mem, beta_c), ic);  // integrate
        const float diff = __fsub_rn(nm, vth);
        const bool  sp   = diff > 0.0f;
        const float s    = sp ? 1.0f : 0.0f;
        mem = sp ? 0.0f : nm;                         // reset-to-zero on spike
        a   = __fadd_rn(__fmul_rn(p_c, a), s);        // adaptation
        vth = __fadd_rn(1.0f, __fmul_rn(b_c, a));     // adaptive threshold
        ps  = s;
        return s;
    };

    asm volatile("s_waitcnt vmcnt(0)" ::: "memory");  // 32-KiB span landed

    // ---- scan: lane L = row L; 2-quad prefetch; spikes in-place ----
    if (lane < ROWSB) {
        const int L7 = lane & 7;
        float4* xb = xbuf + lane * QPR;               // row base (quads)
        float4 p0 = xb[0 ^ L7];
        float4 p1 = xb[1 ^ L7];
        #pragma unroll 2
        for (int t4 = 0; t4 < QPR; t4 += 2) {
            // issue next reads FIRST (in-order DS pipe: ~8 steps of cover)
            float4 n0 = xb[((t4 + 2) & (QPR - 1)) ^ L7];  // wraps harmlessly
            float4 s0;
            s0.x = step(p0.x); s0.y = step(p0.y);
            s0.z = step(p0.z); s0.w = step(p0.w);
            xb[t4 ^ L7] = s0;                         // spikes over consumed x
            float4 n1 = xb[((t4 + 3) & (QPR - 1)) ^ L7];
            float4 s1;
            s1.x = step(p1.x); s1.y = step(p1.y);
            s1.z = step(p1.z); s1.w = step(p1.w);
            xb[(t4 + 1) ^ L7] = s1;
            p0 = n0; p1 = n1;
        }
    }
    // 1-wave block: lockstep exec-mask, in-order LDS -> no barrier needed

    // ---- writeout: 32-KiB contiguous NT burst, lane-permuted LDS read ----
    // out quad o = j*64+lane -> row L=j>>1, q=o&127; LDS holds it at
    // j*64 + (lane ^ ((j>>1)&7)).
    #pragma unroll
    for (int j = 0; j < 2 * ROWSB; ++j) {
        const float4 sv = xbuf[j * 64 + (lane ^ ((j >> 1) & 7))];
        __builtin_nontemporal_store(
            *reinterpret_cast<const f4_nt*>(&sv),
            reinterpret_cast<f4_nt*>(oq + j * 64 + lane));
    }
}

extern "C" void kernel_launch(void* const* d_in, const int* in_sizes, int n_in,
                              void* d_out, int out_size, void* d_ws, size_t ws_size,
                              hipStream_t stream) {
    const float* x    = (const float*)d_in[0];
    const float* beta = (const float*)d_in[1];
    const float* p    = (const float*)d_in[2];
    const float* b    = (const float*)d_in[3];
    float* out        = (float*)d_out;

    const int BN = 64 * 1024;  // rows
    snn_fwd<<<dim3(BN / ROWSB), dim3(64), 0, stream>>>(x, beta, p, b, out);
}